// Round 2
// baseline (712.432 us; speedup 1.0000x reference)
//
#include <hip/hip_runtime.h>
#include <hip/hip_bf16.h>
#include <stdint.h>

// QuantizedLinear NF4: x (4,2048,4096) f32, packed (4096,2048) i32 (one byte
// per int32!), absmax (4096,) f32, bias (4096,) f32 -> out (4,2048,4096) f32.
#define M_DIM 8192
#define N_DIM 4096
#define K_DIM 4096

typedef __bf16 bf16_t;
typedef __attribute__((ext_vector_type(8))) __bf16 bf16x8;
typedef __attribute__((ext_vector_type(4))) __bf16 bf16x4;
typedef __attribute__((ext_vector_type(4))) float f32x4;

__constant__ float NF4_LUT[16] = {
    -1.0f, -0.6961928009986877f, -0.5250730514526367f, -0.39491748809814453f,
    -0.28444138169288635f, -0.18477343022823334f, -0.09105003625154495f, 0.0f,
    0.07958029955625534f, 0.16093020141124725f, 0.24611230194568634f,
    0.33791524171829224f, 0.44070982933044434f, 0.5626170039176941f,
    0.7229568362236023f, 1.0f};

// ---------------------------------------------------------------------------
// Kernel 1: NF4 dequant -> bf16 W (N_DIM x K_DIM row-major, k contiguous).
// LUT via ds_bpermute from lanes 0..15 (avoids divergent constant-mem gather).
// Each thread: 4 packed int32 (16B coalesced load) -> 8 bf16 (16B store).
// ---------------------------------------------------------------------------
__global__ __launch_bounds__(256) void dequant_nf4_kernel(
    const int* __restrict__ packed, const float* __restrict__ absmax,
    bf16_t* __restrict__ W) {
  const int t = blockIdx.x * 256 + threadIdx.x;
  const int row = t >> 9;  // 512 chunks of 8 elems per row
  const int c = t & 511;
  const int lane = threadIdx.x & 63;
  const int lutbits = __float_as_int(NF4_LUT[lane & 15]);  // lane L holds LUT[L&15]

  const int4 p = ((const int4*)packed)[t];
  const float am = absmax[row];
  bf16x8 v;
#pragma unroll
  for (int q = 0; q < 4; ++q) {
    const int byte = (q == 0 ? p.x : q == 1 ? p.y : q == 2 ? p.z : p.w) & 255;
    const float hi =
        __int_as_float(__builtin_amdgcn_ds_bpermute(((byte >> 4) & 15) << 2, lutbits));
    const float lo =
        __int_as_float(__builtin_amdgcn_ds_bpermute((byte & 15) << 2, lutbits));
    v[2 * q] = (bf16_t)(hi * am);
    v[2 * q + 1] = (bf16_t)(lo * am);
  }
  *((bf16x8*)&W[(size_t)row * K_DIM + c * 8]) = v;
}

// ---------------------------------------------------------------------------
// Kernel 2: x f32 -> bf16. Fully coalesced: 16B load, 8B store per thread.
// ---------------------------------------------------------------------------
__global__ __launch_bounds__(256) void cvt_bf16_kernel(
    const float* __restrict__ x, bf16_t* __restrict__ y) {
  const int t = blockIdx.x * 256 + threadIdx.x;  // M_DIM*K_DIM/4 threads
  const float4 a = ((const float4*)x)[t];
  bf16x4 v;
  v[0] = (bf16_t)a.x; v[1] = (bf16_t)a.y; v[2] = (bf16_t)a.z; v[3] = (bf16_t)a.w;
  *((bf16x4*)&y[(size_t)t * 4]) = v;
}

// ---------------------------------------------------------------------------
// Kernel 3: bf16 MFMA GEMM, m97 structure + swizzled staging permutation.
//
// LDS physical layout is pinned by global_load_lds to base + tid*16B. We pick
// WHICH global (row,kchunk) each tid loads so that physical chunk
//   p(r,c) = (r>>4)*64 + c*16 + (r&15)
// Then fragment reads hit chunk (wv*4+i)*64 + lane -> lane-contiguous 1KB,
// 2-way bank aliasing only (free per m136). Kills the 8-way conflicts of the
// naive r*4+c layout (3.35e7 SQ_LDS_BANK_CONFLICT in round 1).
// ---------------------------------------------------------------------------
#define GLD_LDS16(g, l)                                                     \
  __builtin_amdgcn_global_load_lds(                                        \
      (const __attribute__((address_space(1))) void*)(g),                   \
      (__attribute__((address_space(3))) void*)(l), 16, 0, 0)

__global__ __launch_bounds__(256) void gemm_nf4_kernel(
    const bf16_t* __restrict__ A, const bf16_t* __restrict__ B,
    const float* __restrict__ bias, float* __restrict__ C) {
  constexpr int BM = 128, BN = 128, BK = 32;
  __shared__ __align__(16) bf16_t sA[BM * BK];  // 512 chunks of 16B, swizzled
  __shared__ __align__(16) bf16_t sB[BN * BK];

  const int tid = threadIdx.x;
  const int wave = tid >> 6, lane = tid & 63;
  const int wr = wave >> 1, wc = wave & 1;  // 2x2 wave grid
  const int quad = lane >> 4, l15 = lane & 15;

  const int blockM = blockIdx.y * BM;
  const int blockN = blockIdx.x * BN;

  // Staging source for physical chunk p=tid (and p=tid+256 -> row+64):
  //   row = (tid>>6)*16 + (tid&15), kchunk = (tid>>4)&3
  const int sr = ((tid >> 6) << 4) | (tid & 15);
  const int sk = ((tid >> 4) & 3) * 8;
  const bf16_t* gA0 = A + (size_t)(blockM + sr) * K_DIM + sk;
  const bf16_t* gA1 = gA0 + (size_t)64 * K_DIM;
  const bf16_t* gB0 = B + (size_t)(blockN + sr) * K_DIM + sk;
  const bf16_t* gB1 = gB0 + (size_t)64 * K_DIM;
  bf16_t* lA0 = &sA[tid * 8];
  bf16_t* lA1 = &sA[(tid + 256) * 8];
  bf16_t* lB0 = &sB[tid * 8];
  bf16_t* lB1 = &sB[(tid + 256) * 8];

  f32x4 acc[4][4];
#pragma unroll
  for (int i = 0; i < 4; ++i)
#pragma unroll
    for (int j = 0; j < 4; ++j) acc[i][j] = (f32x4)(0.0f);

  for (int k0 = 0; k0 < K_DIM; k0 += BK) {
    GLD_LDS16(gA0 + k0, lA0);
    GLD_LDS16(gA1 + k0, lA1);
    GLD_LDS16(gB0 + k0, lB0);
    GLD_LDS16(gB1 + k0, lB1);
    __syncthreads();

    // Fragment (wave w, tile i): logical row w*64+i*16+l15, chunk quad
    //   -> physical chunk (w*4+i)*64 + lane  (lane-contiguous)
    bf16x8 af[4], bfr[4];
#pragma unroll
    for (int i = 0; i < 4; ++i)
      af[i] = *(const bf16x8*)&sA[((wr * 4 + i) * 64 + lane) * 8];
#pragma unroll
    for (int j = 0; j < 4; ++j)
      bfr[j] = *(const bf16x8*)&sB[((wc * 4 + j) * 64 + lane) * 8];

#pragma unroll
    for (int i = 0; i < 4; ++i)
#pragma unroll
      for (int j = 0; j < 4; ++j)
        acc[i][j] = __builtin_amdgcn_mfma_f32_16x16x32_bf16(af[i], bfr[j],
                                                            acc[i][j], 0, 0, 0);
    __syncthreads();
  }

  // Epilogue: C/D layout col = lane&15 (n), row = quad*4 + reg (m). Fused bias.
#pragma unroll
  for (int j = 0; j < 4; ++j) {
    const int n = blockN + wc * 64 + j * 16 + l15;
    const float bv = bias[n];
#pragma unroll
    for (int i = 0; i < 4; ++i) {
      const int m0 = blockM + wr * 64 + i * 16 + quad * 4;
      f32x4 v = acc[i][j];
      C[(size_t)(m0 + 0) * N_DIM + n] = v[0] + bv;
      C[(size_t)(m0 + 1) * N_DIM + n] = v[1] + bv;
      C[(size_t)(m0 + 2) * N_DIM + n] = v[2] + bv;
      C[(size_t)(m0 + 3) * N_DIM + n] = v[3] + bv;
    }
  }
}

// ---------------------------------------------------------------------------
// Fallback (ws too small): naive on-the-fly dequant GEMM.
// ---------------------------------------------------------------------------
__global__ __launch_bounds__(256) void fallback_kernel(
    const float* __restrict__ x, const int* __restrict__ packed,
    const float* __restrict__ absmax, const float* __restrict__ bias,
    float* __restrict__ out) {
  const int idx = blockIdx.x * 256 + threadIdx.x;
  const int m = idx / N_DIM, n = idx % N_DIM;
  const int* prow = packed + (size_t)n * (K_DIM / 2);
  const float* xr = x + (size_t)m * K_DIM;
  float s = 0.0f;
  for (int p = 0; p < K_DIM / 2; ++p) {
    const int b = prow[p] & 255;
    s += xr[2 * p] * NF4_LUT[(b >> 4) & 15] + xr[2 * p + 1] * NF4_LUT[b & 15];
  }
  out[idx] = s * absmax[n] + bias[n];
}

extern "C" void kernel_launch(void* const* d_in, const int* in_sizes, int n_in,
                              void* d_out, int out_size, void* d_ws,
                              size_t ws_size, hipStream_t stream) {
  const float* x = (const float*)d_in[0];
  const int* packed = (const int*)d_in[1];
  const float* absmax = (const float*)d_in[2];
  const float* bias = (const float*)d_in[3];
  float* out = (float*)d_out;

  const size_t wBytes = (size_t)N_DIM * K_DIM * sizeof(bf16_t);  // 32 MB
  const size_t xBytes = (size_t)M_DIM * K_DIM * sizeof(bf16_t);  // 64 MB
  if (ws_size < wBytes + xBytes) {
    fallback_kernel<<<dim3((M_DIM * N_DIM) / 256), dim3(256), 0, stream>>>(
        x, packed, absmax, bias, out);
    return;
  }

  bf16_t* W = (bf16_t*)d_ws;
  bf16_t* xb = (bf16_t*)((char*)d_ws + wBytes);

  dequant_nf4_kernel<<<dim3((N_DIM * (K_DIM / 2) / 4) / 256), dim3(256), 0,
                       stream>>>(packed, absmax, W);
  cvt_bf16_kernel<<<dim3((M_DIM * K_DIM / 4) / 256), dim3(256), 0, stream>>>(
      x, xb);
  gemm_nf4_kernel<<<dim3(N_DIM / 128, M_DIM / 128), dim3(256), 0, stream>>>(
      xb, W, bias, out);
}

// Round 3
// 539.792 us; speedup vs baseline: 1.3198x; 1.3198x over previous
//
#include <hip/hip_runtime.h>
#include <hip/hip_bf16.h>
#include <stdint.h>

// QuantizedLinear NF4: x (4,2048,4096) f32, packed (4096,2048) i32 (one byte
// per int32), absmax (4096,) f32, bias (4096,) f32 -> out (4,2048,4096) f32.
#define M_DIM 8192
#define N_DIM 4096
#define K_DIM 4096

typedef __bf16 bf16_t;
typedef __attribute__((ext_vector_type(8))) __bf16 bf16x8;
typedef __attribute__((ext_vector_type(4))) __bf16 bf16x4;
typedef __attribute__((ext_vector_type(4))) float f32x4;

__constant__ float NF4_LUT[16] = {
    -1.0f, -0.6961928009986877f, -0.5250730514526367f, -0.39491748809814453f,
    -0.28444138169288635f, -0.18477343022823334f, -0.09105003625154495f, 0.0f,
    0.07958029955625534f, 0.16093020141124725f, 0.24611230194568634f,
    0.33791524171829224f, 0.44070982933044434f, 0.5626170039176941f,
    0.7229568362236023f, 1.0f};

// ---------------------------------------------------------------------------
// Kernel 1: NF4 dequant -> bf16 W (N_DIM x K_DIM row-major). LUT in lanes
// 0..15 via ds_bpermute. 16B coalesced load -> 16B store per thread.
// ---------------------------------------------------------------------------
__global__ __launch_bounds__(256) void dequant_nf4_kernel(
    const int* __restrict__ packed, const float* __restrict__ absmax,
    bf16_t* __restrict__ W) {
  const int t = blockIdx.x * 256 + threadIdx.x;
  const int row = t >> 9;
  const int c = t & 511;
  const int lane = threadIdx.x & 63;
  const int lutbits = __float_as_int(NF4_LUT[lane & 15]);

  const int4 p = ((const int4*)packed)[t];
  const float am = absmax[row];
  bf16x8 v;
#pragma unroll
  for (int q = 0; q < 4; ++q) {
    const int byte = (q == 0 ? p.x : q == 1 ? p.y : q == 2 ? p.z : p.w) & 255;
    const float hi =
        __int_as_float(__builtin_amdgcn_ds_bpermute(((byte >> 4) & 15) << 2, lutbits));
    const float lo =
        __int_as_float(__builtin_amdgcn_ds_bpermute((byte & 15) << 2, lutbits));
    v[2 * q] = (bf16_t)(hi * am);
    v[2 * q + 1] = (bf16_t)(lo * am);
  }
  *((bf16x8*)&W[(size_t)row * K_DIM + c * 8]) = v;
}

// ---------------------------------------------------------------------------
// Kernel 2: x f32 -> bf16. Fully coalesced: 16B load, 8B store per thread.
// ---------------------------------------------------------------------------
__global__ __launch_bounds__(256) void cvt_bf16_kernel(
    const float* __restrict__ x, bf16_t* __restrict__ y) {
  const int t = blockIdx.x * 256 + threadIdx.x;
  const float4 a = ((const float4*)x)[t];
  bf16x4 v;
  v[0] = (bf16_t)a.x; v[1] = (bf16_t)a.y; v[2] = (bf16_t)a.z; v[3] = (bf16_t)a.w;
  *((bf16x4*)&y[(size_t)t * 4]) = v;
}

// ---------------------------------------------------------------------------
// Kernel 3: bf16 MFMA GEMM. XOR-swizzled LDS:
//   physical chunk p (16B) holds logical (row = p>>2, kchunk = (p&3)^((p>>3)&3))
// Staging global pattern is identical to round 1 (4-lane groups cover one 64B
// row segment -> coalesced); fragment read of (rr, quad) hits chunk
//   rr*4 + (quad ^ ((rr>>1)&3)) -> every 8 lanes cover all 8 bank groups once
// -> conflict-free (round 1: 8-way, 3.35e7 conflicts; round 2: conflict-free
// but scattered global -> 520us. This keeps both properties.)
// ---------------------------------------------------------------------------
#define GLD_LDS16(g, l)                                                     \
  __builtin_amdgcn_global_load_lds(                                        \
      (const __attribute__((address_space(1))) void*)(g),                   \
      (__attribute__((address_space(3))) void*)(l), 16, 0, 0)

__global__ __launch_bounds__(256) void gemm_nf4_kernel(
    const bf16_t* __restrict__ A, const bf16_t* __restrict__ B,
    const float* __restrict__ bias, float* __restrict__ C) {
  constexpr int BM = 128, BN = 128, BK = 32;
  __shared__ __align__(16) bf16_t sA[BM * BK];
  __shared__ __align__(16) bf16_t sB[BN * BK];

  const int tid = threadIdx.x;
  const int wave = tid >> 6, lane = tid & 63;
  const int wr = wave >> 1, wc = wave & 1;
  const int quad = lane >> 4, l15 = lane & 15;

  const int blockM = blockIdx.y * BM;
  const int blockN = blockIdx.x * BN;

  // Staging: thread tid -> physical chunk tid (and tid+256 for rows 64..127).
  // Logical source: row = tid>>2, kchunk = (tid&3) ^ ((tid>>3)&3).
  const int sr = tid >> 2;
  const int sk = ((tid & 3) ^ ((tid >> 3) & 3)) * 8;
  const bf16_t* gA0 = A + (size_t)(blockM + sr) * K_DIM + sk;
  const bf16_t* gA1 = gA0 + (size_t)64 * K_DIM;
  const bf16_t* gB0 = B + (size_t)(blockN + sr) * K_DIM + sk;
  const bf16_t* gB1 = gB0 + (size_t)64 * K_DIM;
  bf16_t* lA0 = &sA[tid * 8];
  bf16_t* lA1 = &sA[(tid + 256) * 8];
  bf16_t* lB0 = &sB[tid * 8];
  bf16_t* lB1 = &sB[(tid + 256) * 8];

  f32x4 acc[4][4];
#pragma unroll
  for (int i = 0; i < 4; ++i)
#pragma unroll
    for (int j = 0; j < 4; ++j) acc[i][j] = (f32x4)(0.0f);

  // Fragment-read physical chunk offset within row: lane-constant.
  const int cphys = quad ^ ((l15 >> 1) & 3);

  for (int k0 = 0; k0 < K_DIM; k0 += BK) {
    GLD_LDS16(gA0 + k0, lA0);
    GLD_LDS16(gA1 + k0, lA1);
    GLD_LDS16(gB0 + k0, lB0);
    GLD_LDS16(gB1 + k0, lB1);
    __syncthreads();

    bf16x8 af[4], bfr[4];
#pragma unroll
    for (int i = 0; i < 4; ++i) {
      const int rr = wr * 64 + i * 16 + l15;
      af[i] = *(const bf16x8*)&sA[(rr * 4 + cphys) * 8];
    }
#pragma unroll
    for (int j = 0; j < 4; ++j) {
      const int rr = wc * 64 + j * 16 + l15;
      bfr[j] = *(const bf16x8*)&sB[(rr * 4 + cphys) * 8];
    }

#pragma unroll
    for (int i = 0; i < 4; ++i)
#pragma unroll
      for (int j = 0; j < 4; ++j)
        acc[i][j] = __builtin_amdgcn_mfma_f32_16x16x32_bf16(af[i], bfr[j],
                                                            acc[i][j], 0, 0, 0);
    __syncthreads();
  }

  // Epilogue: C/D layout col = lane&15 (n), row = quad*4 + reg (m). Fused bias.
#pragma unroll
  for (int j = 0; j < 4; ++j) {
    const int n = blockN + wc * 64 + j * 16 + l15;
    const float bv = bias[n];
#pragma unroll
    for (int i = 0; i < 4; ++i) {
      const int m0 = blockM + wr * 64 + i * 16 + quad * 4;
      f32x4 v = acc[i][j];
      C[(size_t)(m0 + 0) * N_DIM + n] = v[0] + bv;
      C[(size_t)(m0 + 1) * N_DIM + n] = v[1] + bv;
      C[(size_t)(m0 + 2) * N_DIM + n] = v[2] + bv;
      C[(size_t)(m0 + 3) * N_DIM + n] = v[3] + bv;
    }
  }
}

// ---------------------------------------------------------------------------
// Fallback (ws too small): naive on-the-fly dequant GEMM.
// ---------------------------------------------------------------------------
__global__ __launch_bounds__(256) void fallback_kernel(
    const float* __restrict__ x, const int* __restrict__ packed,
    const float* __restrict__ absmax, const float* __restrict__ bias,
    float* __restrict__ out) {
  const int idx = blockIdx.x * 256 + threadIdx.x;
  const int m = idx / N_DIM, n = idx % N_DIM;
  const int* prow = packed + (size_t)n * (K_DIM / 2);
  const float* xr = x + (size_t)m * K_DIM;
  float s = 0.0f;
  for (int p = 0; p < K_DIM / 2; ++p) {
    const int b = prow[p] & 255;
    s += xr[2 * p] * NF4_LUT[(b >> 4) & 15] + xr[2 * p + 1] * NF4_LUT[b & 15];
  }
  out[idx] = s * absmax[n] + bias[n];
}

extern "C" void kernel_launch(void* const* d_in, const int* in_sizes, int n_in,
                              void* d_out, int out_size, void* d_ws,
                              size_t ws_size, hipStream_t stream) {
  const float* x = (const float*)d_in[0];
  const int* packed = (const int*)d_in[1];
  const float* absmax = (const float*)d_in[2];
  const float* bias = (const float*)d_in[3];
  float* out = (float*)d_out;

  const size_t wBytes = (size_t)N_DIM * K_DIM * sizeof(bf16_t);  // 32 MB
  const size_t xBytes = (size_t)M_DIM * K_DIM * sizeof(bf16_t);  // 64 MB
  if (ws_size < wBytes + xBytes) {
    fallback_kernel<<<dim3((M_DIM * N_DIM) / 256), dim3(256), 0, stream>>>(
        x, packed, absmax, bias, out);
    return;
  }

  bf16_t* W = (bf16_t*)d_ws;
  bf16_t* xb = (bf16_t*)((char*)d_ws + wBytes);

  dequant_nf4_kernel<<<dim3((N_DIM * (K_DIM / 2) / 4) / 256), dim3(256), 0,
                       stream>>>(packed, absmax, W);
  cvt_bf16_kernel<<<dim3((M_DIM * K_DIM / 4) / 256), dim3(256), 0, stream>>>(
      x, xb);
  gemm_nf4_kernel<<<dim3(N_DIM / 128, M_DIM / 128), dim3(256), 0, stream>>>(
      xb, W, bias, out);
}